// Round 7
// baseline (140.530 us; speedup 1.0000x reference)
//
#include <hip/hip_runtime.h>

// AdderNet 2D: out[n,co,ho,wo] = -sum_{ci,kh,kw} |x_pad - w|
// x: [16,64,56,56] f32, w: [64,64,3,3] f32, out: [16,64,56,56] f32.
// VALU issue floor ~47 us @2.4GHz (2 instr per reduce elem).
//
// R6 analysis: residency caps ~16 waves/CU; real VALU busy ~40%. Latency-
// bound on the per-ci chain (wt load -> ds_read -> short VALU burst).
// R7: 4 output rows per wave (R5 inner loop) under the proven no-spill
// (256,4) regime: 576 VALU per ci per wave (2x burst), 6 row-reads
// (240 B) -> LDS-bytes/VALU 0.67 -> 0.42. Tile 4x8, 4 ci-quarter waves,
// grid 1568.

#define NCI   64
#define LDSW  12    // padded LDS row stride (48B): b128-aligned at 0,4; b64 at 8

// pre-kernel: w[co][ci][k] -> wt[ci][k4][co][4]  (k = k4*4+jj, k>=9 zero-pad)
__global__ void wt_transpose_kernel(const float* __restrict__ w, float* __restrict__ wt) {
    int idx = blockIdx.x * 256 + threadIdx.x;   // 64*3*64*4 = 49152
    if (idx >= NCI * 3 * 64 * 4) return;
    int ci  = idx / 768;
    int rem = idx % 768;
    int k4  = rem / 256;
    int r2  = rem % 256;
    int co  = r2 / 4;
    int jj  = r2 % 4;
    int k   = k4 * 4 + jj;
    wt[idx] = (k < 9) ? w[(co * NCI + ci) * 9 + k] : 0.0f;
}

#define LOADROW(xr, base)                                   \
    {                                                       \
        float4 A = *(const float4*)(base);                  \
        float4 B = *(const float4*)((base) + 4);            \
        float2 C = *(const float2*)((base) + 8);            \
        xr[0]=A.x; xr[1]=A.y; xr[2]=A.z; xr[3]=A.w;         \
        xr[4]=B.x; xr[5]=B.y; xr[6]=B.z; xr[7]=B.w;         \
        xr[8]=C.x; xr[9]=C.y;                               \
    }

#define TAPS(i, kh)                                         \
    _Pragma("unroll")                                       \
    for (int kw = 0; kw < 3; ++kw) {                        \
        const float wv_ = wreg[(kh)*3 + kw];                \
        _Pragma("unroll")                                   \
        for (int s = 0; s < 8; ++s)                         \
            acc[i][s] += fabsf(xr[s + kw] - wv_);           \
    }

template <bool USE_WT>
__global__ __launch_bounds__(256, 4) void adder2d_main(
    const float* __restrict__ x, const float* __restrict__ w,
    const float* __restrict__ wt, float* __restrict__ out)
{
    // 18 KiB: x slab [64 ci][6 rows][LDSW]; overlaid by merge buf (2x8 KiB)
    __shared__ float lds[NCI * 6 * LDSW];

    const int bid = blockIdx.x;
    const int n   = bid / 98;          // 14 row-tiles * 7 col-tiles
    const int t   = bid % 98;
    const int r0  = (t / 7) * 4;
    const int c0  = (t % 7) * 8;

    const int tid  = threadIdx.x;
    const int lane = tid & 63;         // = co
    const int q    = tid >> 6;         // ci quarter: ci q*16 .. q*16+15

    // ---- stage x: rows r0-1..r0+4 (6), cols c0-1..c0+8 (10), all ci ----
    const float* xn = x + (size_t)n * NCI * 56 * 56;
    #pragma unroll
    for (int it = 0; it < 15; ++it) {            // 3840 = 256*15 exactly
        int idx = it * 256 + tid;
        int ci  = idx / 60;
        int rem = idx % 60;
        int r   = rem / 10;
        int c   = rem % 10;
        int gh  = r0 + r - 1;
        int gw  = c0 + c - 1;
        float v = 0.f;
        if ((unsigned)gh < 56u && (unsigned)gw < 56u)
            v = xn[(ci * 56 + gh) * 56 + gw];
        lds[(ci * 6 + r) * LDSW + c] = v;
    }
    __syncthreads();

    float acc[4][8];
    #pragma unroll
    for (int i = 0; i < 4; ++i)
        #pragma unroll
        for (int s = 0; s < 8; ++s) acc[i][s] = 0.f;

    const float4* wt4 = (const float4*)wt;
    const int ci0 = q * 16;

    for (int ci = ci0; ci < ci0 + 16; ++ci) {
        float wreg[12];
        if (USE_WT) {
            #pragma unroll
            for (int k4 = 0; k4 < 3; ++k4) {
                float4 qv = wt4[(ci * 3 + k4) * 64 + lane];
                wreg[k4*4+0] = qv.x; wreg[k4*4+1] = qv.y;
                wreg[k4*4+2] = qv.z; wreg[k4*4+3] = qv.w;
            }
        } else {
            #pragma unroll
            for (int k = 0; k < 9; ++k)
                wreg[k] = w[(lane * NCI + ci) * 9 + k];
        }

        const float* slab = &lds[(ci * 6) * LDSW];

        // stream 6 x-rows; row j feeds acc[i] for i = j-2..j, kh = j-i
        { float xr[10]; LOADROW(xr, slab);            TAPS(0,0) }
        { float xr[10]; LOADROW(xr, slab + 1*LDSW);   TAPS(0,1) TAPS(1,0) }
        { float xr[10]; LOADROW(xr, slab + 2*LDSW);   TAPS(0,2) TAPS(1,1) TAPS(2,0) }
        { float xr[10]; LOADROW(xr, slab + 3*LDSW);   TAPS(1,2) TAPS(2,1) TAPS(3,0) }
        { float xr[10]; LOADROW(xr, slab + 4*LDSW);   TAPS(2,2) TAPS(3,1) }
        { float xr[10]; LOADROW(xr, slab + 5*LDSW);   TAPS(3,2) }
    }

    // ---- 4-way ci merge, 2-step tree (overlay fits 18 KiB) ----
    __syncthreads();   // all x reads done; overlay safe
    // step 1: q2 -> red[0], q3 -> red[2048]
    if (q >= 2) {
        float* red = &lds[(q - 2) * 2048];
        #pragma unroll
        for (int i = 0; i < 4; ++i)
            #pragma unroll
            for (int s = 0; s < 8; ++s)
                red[(i * 8 + s) * 64 + lane] = acc[i][s];
    }
    __syncthreads();
    if (q < 2) {
        const float* red = &lds[q * 2048];
        #pragma unroll
        for (int i = 0; i < 4; ++i)
            #pragma unroll
            for (int s = 0; s < 8; ++s)
                acc[i][s] += red[(i * 8 + s) * 64 + lane];
    }
    __syncthreads();
    // step 2: q1 -> red[0]
    if (q == 1) {
        float* red = &lds[0];
        #pragma unroll
        for (int i = 0; i < 4; ++i)
            #pragma unroll
            for (int s = 0; s < 8; ++s)
                red[(i * 8 + s) * 64 + lane] = acc[i][s];
    }
    __syncthreads();
    if (q == 0) {
        const float* red = &lds[0];
        #pragma unroll
        for (int i = 0; i < 4; ++i)
            #pragma unroll
            for (int s = 0; s < 8; ++s)
                acc[i][s] += red[(i * 8 + s) * 64 + lane];

        float* op = out + (((size_t)n * 64 + lane) * 56 + r0) * 56 + c0;
        #pragma unroll
        for (int i = 0; i < 4; ++i) {
            *(float4*)(op + i * 56)     = make_float4(-acc[i][0], -acc[i][1], -acc[i][2], -acc[i][3]);
            *(float4*)(op + i * 56 + 4) = make_float4(-acc[i][4], -acc[i][5], -acc[i][6], -acc[i][7]);
        }
    }
}

extern "C" void kernel_launch(void* const* d_in, const int* in_sizes, int n_in,
                              void* d_out, int out_size, void* d_ws, size_t ws_size,
                              hipStream_t stream) {
    const float* x = (const float*)d_in[0];
    const float* w = (const float*)d_in[1];
    float* out = (float*)d_out;
    float* wt  = (float*)d_ws;

    const size_t wt_bytes = (size_t)NCI * 3 * 64 * 4 * sizeof(float);  // 192 KiB
    const bool use_wt = ws_size >= wt_bytes;

    if (use_wt) {
        wt_transpose_kernel<<<(NCI * 3 * 64 * 4 + 255) / 256, 256, 0, stream>>>(w, wt);
        adder2d_main<true><<<16 * 98, 256, 0, stream>>>(x, w, wt, out);
    } else {
        adder2d_main<false><<<16 * 98, 256, 0, stream>>>(x, w, wt, out);
    }
}

// Round 8
// 129.573 us; speedup vs baseline: 1.0846x; 1.0846x over previous
//
#include <hip/hip_runtime.h>

// AdderNet 2D: out[n,co,ho,wo] = -sum_{ci,kh,kw} |x_pad - w|
// x: [16,64,56,56] f32, w: [64,64,3,3] f32, out: [16,64,56,56] f32.
// VALU issue floor ~47 us @2.4GHz (2 instr/reduce-elem: v_sub + v_add(|.|)).
//
// Evidence through R7: dur tracks residency; residency hovers ~4 BLOCKS/CU
// regardless of LDS/VGPR allowances; real VALU busy ~41% (gfx94x VALUBusy
// formula double-counts on SIMD-32). R8: same proven inner loop as R6
// (2-row tile, 4 x-rows streamed, no spill) but 8 waves per block
// (8 ci-eighths) -> if ~4 blocks/CU keep residing, 32 waves/CU.
//
// lane = co. Block = 512 thr = 8 waves, tile 2x8, grid 3136 (12.25 blk/CU).
// 8-way ci merge via 3-step LDS tree overlaid on the x slab.

#define NCI   64
#define LDSW  12    // padded LDS row stride (48B): float4-aligned rows

// pre-kernel: w[co][ci][k] -> wt[ci][k4][co][4]  (k = k4*4+jj, k>=9 zero-pad)
__global__ void wt_transpose_kernel(const float* __restrict__ w, float* __restrict__ wt) {
    int idx = blockIdx.x * 256 + threadIdx.x;   // 64*3*64*4 = 49152
    if (idx >= NCI * 3 * 64 * 4) return;
    int ci  = idx / 768;
    int rem = idx % 768;
    int k4  = rem / 256;
    int r2  = rem % 256;
    int co  = r2 / 4;
    int jj  = r2 % 4;
    int k   = k4 * 4 + jj;
    wt[idx] = (k < 9) ? w[(co * NCI + ci) * 9 + k] : 0.0f;
}

#define LOADROW(xr, base)                                   \
    {                                                       \
        float4 A = *(const float4*)(base);                  \
        float4 B = *(const float4*)((base) + 4);            \
        float2 C = *(const float2*)((base) + 8);            \
        xr[0]=A.x; xr[1]=A.y; xr[2]=A.z; xr[3]=A.w;         \
        xr[4]=B.x; xr[5]=B.y; xr[6]=B.z; xr[7]=B.w;         \
        xr[8]=C.x; xr[9]=C.y;                               \
    }

#define TAPS(acc, xr, wreg, kh)                             \
    _Pragma("unroll")                                       \
    for (int kw = 0; kw < 3; ++kw) {                        \
        const float wv_ = wreg[(kh)*3 + kw];                \
        _Pragma("unroll")                                   \
        for (int s = 0; s < 8; ++s)                         \
            acc[s] += fabsf(xr[s + kw] - wv_);              \
    }

template <bool USE_WT>
__global__ __launch_bounds__(512, 4) void adder2d_main(
    const float* __restrict__ x, const float* __restrict__ w,
    const float* __restrict__ wt, float* __restrict__ out)
{
    // 16 KiB: x slab [64 ci][4 rows][LDSW] = 3072 f; merge tree needs 4096 f
    __shared__ float lds[4096];

    const int bid = blockIdx.x;
    const int n   = bid / 196;         // 28 row-tiles * 7 col-tiles
    const int t   = bid % 196;
    const int r0  = (t / 7) * 2;
    const int c0  = (t % 7) * 8;

    const int tid  = threadIdx.x;
    const int lane = tid & 63;         // = co
    const int q    = tid >> 6;         // wave 0..7 = ci eighth: q*8 .. q*8+7

    // ---- stage x: rows r0-1..r0+2 (4), cols c0-1..c0+8 (10), all ci ----
    const float* xn = x + (size_t)n * NCI * 56 * 56;
    #pragma unroll
    for (int it = 0; it < 5; ++it) {             // 2560 = 512*5 exactly
        int idx = it * 512 + tid;
        int ci  = idx / 40;
        int rem = idx % 40;
        int r   = rem / 10;
        int c   = rem % 10;
        int gh  = r0 + r - 1;
        int gw  = c0 + c - 1;
        float v = 0.f;
        if ((unsigned)gh < 56u && (unsigned)gw < 56u)
            v = xn[(ci * 56 + gh) * 56 + gw];
        lds[(ci * 4 + r) * LDSW + c] = v;
    }
    __syncthreads();

    float acc0[8], acc1[8];
    #pragma unroll
    for (int s = 0; s < 8; ++s) { acc0[s] = 0.f; acc1[s] = 0.f; }

    const float4* wt4 = (const float4*)wt;
    const int ci0 = q * 8;

    for (int ci = ci0; ci < ci0 + 8; ++ci) {
        float wreg[12];
        if (USE_WT) {
            #pragma unroll
            for (int k4 = 0; k4 < 3; ++k4) {
                float4 qv = wt4[(ci * 3 + k4) * 64 + lane];
                wreg[k4*4+0] = qv.x; wreg[k4*4+1] = qv.y;
                wreg[k4*4+2] = qv.z; wreg[k4*4+3] = qv.w;
            }
        } else {
            #pragma unroll
            for (int k = 0; k < 9; ++k)
                wreg[k] = w[(lane * NCI + ci) * 9 + k];
        }

        const float* rb = &lds[(ci * 4) * LDSW];

        // stream 4 x-rows; row j feeds acc0 (kh=j, j<=2) and acc1 (kh=j-1, j>=1)
        {
            float xr[10]; LOADROW(xr, rb);
            TAPS(acc0, xr, wreg, 0);
        }
        {
            float xr[10]; LOADROW(xr, rb + LDSW);
            TAPS(acc0, xr, wreg, 1);
            TAPS(acc1, xr, wreg, 0);
        }
        {
            float xr[10]; LOADROW(xr, rb + 2 * LDSW);
            TAPS(acc0, xr, wreg, 2);
            TAPS(acc1, xr, wreg, 1);
        }
        {
            float xr[10]; LOADROW(xr, rb + 3 * LDSW);
            TAPS(acc1, xr, wreg, 2);
        }
    }

    // ---- 8-way ci merge: 3-step tree in LDS (bufs of 16x64 = 4 KiB) ----
    __syncthreads();   // all x reads done; overlay safe
    // step 1: q=4..7 -> buf[q-4]
    if (q >= 4) {
        float* red = &lds[(q - 4) * 1024];
        #pragma unroll
        for (int s = 0; s < 8; ++s) {
            red[(s    ) * 64 + lane] = acc0[s];
            red[(s + 8) * 64 + lane] = acc1[s];
        }
    }
    __syncthreads();
    if (q < 4) {
        const float* red = &lds[q * 1024];
        #pragma unroll
        for (int s = 0; s < 8; ++s) {
            acc0[s] += red[(s    ) * 64 + lane];
            acc1[s] += red[(s + 8) * 64 + lane];
        }
    }
    __syncthreads();
    // step 2: q=2,3 -> buf[q-2]
    if (q == 2 || q == 3) {
        float* red = &lds[(q - 2) * 1024];
        #pragma unroll
        for (int s = 0; s < 8; ++s) {
            red[(s    ) * 64 + lane] = acc0[s];
            red[(s + 8) * 64 + lane] = acc1[s];
        }
    }
    __syncthreads();
    if (q < 2) {
        const float* red = &lds[q * 1024];
        #pragma unroll
        for (int s = 0; s < 8; ++s) {
            acc0[s] += red[(s    ) * 64 + lane];
            acc1[s] += red[(s + 8) * 64 + lane];
        }
    }
    __syncthreads();
    // step 3: q=1 -> buf[0]
    if (q == 1) {
        float* red = &lds[0];
        #pragma unroll
        for (int s = 0; s < 8; ++s) {
            red[(s    ) * 64 + lane] = acc0[s];
            red[(s + 8) * 64 + lane] = acc1[s];
        }
    }
    __syncthreads();
    if (q == 0) {
        const float* red = &lds[0];
        #pragma unroll
        for (int s = 0; s < 8; ++s) {
            acc0[s] += red[(s    ) * 64 + lane];
            acc1[s] += red[(s + 8) * 64 + lane];
        }
        float* op = out + (((size_t)n * 64 + lane) * 56 + r0) * 56 + c0;
        *(float4*)(op)          = make_float4(-acc0[0], -acc0[1], -acc0[2], -acc0[3]);
        *(float4*)(op + 4)      = make_float4(-acc0[4], -acc0[5], -acc0[6], -acc0[7]);
        *(float4*)(op + 56)     = make_float4(-acc1[0], -acc1[1], -acc1[2], -acc1[3]);
        *(float4*)(op + 56 + 4) = make_float4(-acc1[4], -acc1[5], -acc1[6], -acc1[7]);
    }
}

extern "C" void kernel_launch(void* const* d_in, const int* in_sizes, int n_in,
                              void* d_out, int out_size, void* d_ws, size_t ws_size,
                              hipStream_t stream) {
    const float* x = (const float*)d_in[0];
    const float* w = (const float*)d_in[1];
    float* out = (float*)d_out;
    float* wt  = (float*)d_ws;

    const size_t wt_bytes = (size_t)NCI * 3 * 64 * 4 * sizeof(float);  // 192 KiB
    const bool use_wt = ws_size >= wt_bytes;

    if (use_wt) {
        wt_transpose_kernel<<<(NCI * 3 * 64 * 4 + 255) / 256, 256, 0, stream>>>(w, wt);
        adder2d_main<true><<<16 * 196, 512, 0, stream>>>(x, w, wt, out);
    } else {
        adder2d_main<false><<<16 * 196, 512, 0, stream>>>(x, w, wt, out);
    }
}